// Round 6
// baseline (246.857 us; speedup 1.0000x reference)
//
#include <hip/hip_runtime.h>

typedef __attribute__((ext_vector_type(8))) short short8;
typedef __attribute__((ext_vector_type(4))) float floatx4;

#define TOKENS 2048
#define IN_F   4096
#define OUT_F  4096
#define NITER  20
#define BK     32

#define INV_2PI 0.15915494309189535f
#define TWO_PI  6.283185307179586f

// round-to-nearest-even f32 -> bf16 bits
__device__ __forceinline__ unsigned short f2bf(float f) {
    unsigned int u = __builtin_bit_cast(unsigned int, f);
    u += 0x7fffu + ((u >> 16) & 1u);
    return (unsigned short)(u >> 16);
}

// one fractal step in REVOLUTION units: v' = a*v + (b/2pi)*sin(2pi*v)
__device__ __forceinline__ void step4(float4& v, float a, float bc) {
    v.x = __builtin_fmaf(bc, __builtin_amdgcn_sinf(v.x), a * v.x);
    v.y = __builtin_fmaf(bc, __builtin_amdgcn_sinf(v.y), a * v.y);
    v.z = __builtin_fmaf(bc, __builtin_amdgcn_sinf(v.z), a * v.z);
    v.w = __builtin_fmaf(bc, __builtin_amdgcn_sinf(v.w), a * v.w);
}

#define WBLOCKS (OUT_F * IN_F / 8 / 256)   // 8192
#define XBLOCKS (TOKENS * IN_F / 8 / 256)  // 4096

// Fused: blocks [0,8192) transcribe seed->w_bf (20 iters); [8192,12288) cast x->x_bf.
__global__ __launch_bounds__(256) void transcribe_fused_kernel(
    const float4* __restrict__ seed, const float4* __restrict__ xin,
    const float* __restrict__ da, const float* __restrict__ db,
    short8* __restrict__ w_out, short8* __restrict__ x_out)
{
    const int b = blockIdx.x;
    short8 o;
    if (b < WBLOCKS) {
        int i = b * 256 + threadIdx.x;
        float4 u = seed[2 * i];
        float4 v = seed[2 * i + 1];
        u.x *= INV_2PI; u.y *= INV_2PI; u.z *= INV_2PI; u.w *= INV_2PI;
        v.x *= INV_2PI; v.y *= INV_2PI; v.z *= INV_2PI; v.w *= INV_2PI;
#pragma unroll
        for (int t = 0; t < NITER; t++) {
            float a = da[t], bc = db[t] * INV_2PI;
            step4(u, a, bc);
            step4(v, a, bc);
        }
        o[0] = (short)f2bf(u.x * TWO_PI); o[1] = (short)f2bf(u.y * TWO_PI);
        o[2] = (short)f2bf(u.z * TWO_PI); o[3] = (short)f2bf(u.w * TWO_PI);
        o[4] = (short)f2bf(v.x * TWO_PI); o[5] = (short)f2bf(v.y * TWO_PI);
        o[6] = (short)f2bf(v.z * TWO_PI); o[7] = (short)f2bf(v.w * TWO_PI);
        w_out[i] = o;
    } else {
        int i = (b - WBLOCKS) * 256 + threadIdx.x;
        float4 u = xin[2 * i];
        float4 v = xin[2 * i + 1];
        o[0] = (short)f2bf(u.x); o[1] = (short)f2bf(u.y);
        o[2] = (short)f2bf(u.z); o[3] = (short)f2bf(u.w);
        o[4] = (short)f2bf(v.x); o[5] = (short)f2bf(v.y);
        o[6] = (short)f2bf(v.z); o[7] = (short)f2bf(v.w);
        x_out[i] = o;
    }
}

// async 16B global -> LDS (LDS dest = wave-uniform base + lane*16, enforced below)
__device__ __forceinline__ void g2l16(const ushort* g, ushort* l) {
    __builtin_amdgcn_global_load_lds(
        (const __attribute__((address_space(1))) unsigned int*)g,
        (__attribute__((address_space(3))) unsigned int*)l, 16, 0, 0);
}

// C[M,N] = A[M,K] * B[N,K]^T + bias[N];  A,B bf16 (bits), C f32.
// 128x128 block tile, BK=32, DOUBLE-BUFFERED LDS (2 x (8+8) KB = 32 KB)
// -> 4 blocks/CU (vs 2 at BK=64/64KB in R5). Dbuf keeps the stage->drain
// overlap; 2x resident blocks cover the residual per-window barrier exposure
// (cross-block overlap, m114). Swizzle = R2/R3-proven zero-conflict scheme:
// physical 16B segment p of row r holds logical segment p ^ ((r>>1)&3)
// (applied global-source side + ds_read side; LDS dest stays linear).
__global__ __launch_bounds__(256, 4) void gemm_bt_kernel(
    const ushort* __restrict__ A,
    const ushort* __restrict__ B,
    const float* __restrict__ bias,
    float* __restrict__ C)
{
    __shared__ ushort As[2][128 * BK];   // 2 x 8 KiB
    __shared__ ushort Bs[2][128 * BK];   // 2 x 8 KiB

    const int tid  = threadIdx.x;
    const int lane = tid & 63;
    const int wid  = tid >> 6;
    const int bn   = blockIdx.x;
    const int bm   = blockIdx.y;
    const int wm   = (wid >> 1) << 6;    // 0/64
    const int wn   = (wid & 1) << 6;     // 0/64
    const int fm   = lane & 15;
    // swizzled ds_read k-offset: logical seg = quad, physical = quad ^ ((r>>1)&3),
    // and (r>>1)&3 == (fm>>1)&3 for all rows we touch (offsets mult of 16/64)
    const int fkd  = (((lane >> 4) ^ ((fm >> 1) & 3)) << 3);

    // staging: thread t covers physical 16B segment (t&3) of row (t>>2)
    const int row0 = tid >> 2;              // 0..63
    const int psg  = tid & 3;
    const int gsg  = (psg ^ ((row0 >> 1) & 3)) << 3;  // global elem offset
    const int lsg  = psg << 3;                        // LDS elem offset (linear)

    const ushort* gA = A + (size_t)(bm * 128) * IN_F;
    const ushort* gB = B + (size_t)(bn * 128) * IN_F;

    floatx4 acc[4][4];
#pragma unroll
    for (int i = 0; i < 4; i++)
#pragma unroll
        for (int j = 0; j < 4; j++)
            acc[i][j] = (floatx4){0.f, 0.f, 0.f, 0.f};

#define STAGE(k0v, bufi)                                                       \
    {                                                                          \
        g2l16(gA + (size_t)row0 * IN_F + (k0v) + gsg,                          \
              &As[bufi][row0 * BK + lsg]);                                     \
        g2l16(gA + (size_t)(row0 + 64) * IN_F + (k0v) + gsg,                   \
              &As[bufi][(row0 + 64) * BK + lsg]);                              \
        g2l16(gB + (size_t)row0 * IN_F + (k0v) + gsg,                          \
              &Bs[bufi][row0 * BK + lsg]);                                     \
        g2l16(gB + (size_t)(row0 + 64) * IN_F + (k0v) + gsg,                   \
              &Bs[bufi][(row0 + 64) * BK + lsg]);                              \
    }

#define COMPUTE(bufi)                                                          \
    {                                                                          \
        short8 af[4], bf[4];                                                   \
        _Pragma("unroll")                                                      \
        for (int i = 0; i < 4; i++) {                                          \
            af[i] = *(const short8*)&As[bufi][(wm + i * 16 + fm) * BK + fkd];  \
            bf[i] = *(const short8*)&Bs[bufi][(wn + i * 16 + fm) * BK + fkd];  \
        }                                                                      \
        _Pragma("unroll")                                                      \
        for (int i = 0; i < 4; i++)                                            \
            _Pragma("unroll")                                                  \
            for (int j = 0; j < 4; j++)                                        \
                acc[i][j] = __builtin_amdgcn_mfma_f32_16x16x32_bf16(           \
                    af[i], bf[j], acc[i][j], 0, 0, 0);                         \
    }

    STAGE(0, 0);
    __syncthreads();
    STAGE(BK, 1);
    COMPUTE(0);
    __syncthreads();
    // 63 pairs: slabs 64..4064
    for (int k0 = 2 * BK; k0 < IN_F; k0 += 2 * BK) {
        STAGE(k0, 0);
        COMPUTE(1);
        __syncthreads();
        STAGE(k0 + BK, 1);
        COMPUTE(0);
        __syncthreads();
    }
    COMPUTE(1);

#undef STAGE
#undef COMPUTE

    // epilogue: C/D layout col = lane&15, row = (lane>>4)*4 + reg  [m89-verified]
    const int cn = lane & 15;
    const int cm = (lane >> 4) << 2;
    float bv[4];
#pragma unroll
    for (int j = 0; j < 4; j++)
        bv[j] = bias[bn * 128 + wn + j * 16 + cn];
#pragma unroll
    for (int i = 0; i < 4; i++) {
#pragma unroll
        for (int r = 0; r < 4; r++) {
            int m = bm * 128 + wm + i * 16 + cm + r;
            float* crow = C + (size_t)m * OUT_F + bn * 128 + wn + cn;
#pragma unroll
            for (int j = 0; j < 4; j++)
                crow[j * 16] = acc[i][j][r] + bv[j];
        }
    }
}

extern "C" void kernel_launch(void* const* d_in, const int* in_sizes, int n_in,
                              void* d_out, int out_size, void* d_ws, size_t ws_size,
                              hipStream_t stream) {
    const float* x    = (const float*)d_in[0];   // [2048, 4096]
    const float* seed = (const float*)d_in[1];   // [4096, 4096]
    const float* da   = (const float*)d_in[2];   // [20]
    const float* db   = (const float*)d_in[3];   // [20]
    const float* bias = (const float*)d_in[4];   // [4096]
    float* out        = (float*)d_out;           // [2048, 4096]

    ushort* w_bf = (ushort*)d_ws;                      // 32 MiB
    ushort* x_bf = w_bf + (size_t)OUT_F * IN_F;        // 16 MiB

    transcribe_fused_kernel<<<WBLOCKS + XBLOCKS, 256, 0, stream>>>(
        (const float4*)seed, (const float4*)x, da, db,
        (short8*)w_bf, (short8*)x_bf);

    dim3 grid(OUT_F / 128, TOKENS / 128);  // (32, 16) = 512 blocks
    gemm_bt_kernel<<<grid, 256, 0, stream>>>(x_bf, w_bf, bias, out);
}

// Round 7
// 215.921 us; speedup vs baseline: 1.1433x; 1.1433x over previous
//
#include <hip/hip_runtime.h>

typedef __attribute__((ext_vector_type(8))) short short8;
typedef __attribute__((ext_vector_type(4))) float floatx4;

#define TOKENS 2048
#define IN_F   4096
#define OUT_F  4096
#define NITER  20
#define BK     64

#define INV_2PI 0.15915494309189535f
#define TWO_PI  6.283185307179586f

// round-to-nearest-even f32 -> bf16 bits
__device__ __forceinline__ unsigned short f2bf(float f) {
    unsigned int u = __builtin_bit_cast(unsigned int, f);
    u += 0x7fffu + ((u >> 16) & 1u);
    return (unsigned short)(u >> 16);
}

// one fractal step in REVOLUTION units: v' = a*v + (b/2pi)*sin(2pi*v)
__device__ __forceinline__ void step4(float4& v, float a, float bc) {
    v.x = __builtin_fmaf(bc, __builtin_amdgcn_sinf(v.x), a * v.x);
    v.y = __builtin_fmaf(bc, __builtin_amdgcn_sinf(v.y), a * v.y);
    v.z = __builtin_fmaf(bc, __builtin_amdgcn_sinf(v.z), a * v.z);
    v.w = __builtin_fmaf(bc, __builtin_amdgcn_sinf(v.w), a * v.w);
}

#define WBLOCKS (OUT_F * IN_F / 8 / 256)   // 8192
#define XBLOCKS (TOKENS * IN_F / 8 / 256)  // 4096

// Fused: blocks [0,8192) transcribe seed->w_bf (20 iters); [8192,12288) cast x->x_bf.
__global__ __launch_bounds__(256) void transcribe_fused_kernel(
    const float4* __restrict__ seed, const float4* __restrict__ xin,
    const float* __restrict__ da, const float* __restrict__ db,
    short8* __restrict__ w_out, short8* __restrict__ x_out)
{
    const int b = blockIdx.x;
    short8 o;
    if (b < WBLOCKS) {
        int i = b * 256 + threadIdx.x;
        float4 u = seed[2 * i];
        float4 v = seed[2 * i + 1];
        u.x *= INV_2PI; u.y *= INV_2PI; u.z *= INV_2PI; u.w *= INV_2PI;
        v.x *= INV_2PI; v.y *= INV_2PI; v.z *= INV_2PI; v.w *= INV_2PI;
#pragma unroll
        for (int t = 0; t < NITER; t++) {
            float a = da[t], bc = db[t] * INV_2PI;
            step4(u, a, bc);
            step4(v, a, bc);
        }
        o[0] = (short)f2bf(u.x * TWO_PI); o[1] = (short)f2bf(u.y * TWO_PI);
        o[2] = (short)f2bf(u.z * TWO_PI); o[3] = (short)f2bf(u.w * TWO_PI);
        o[4] = (short)f2bf(v.x * TWO_PI); o[5] = (short)f2bf(v.y * TWO_PI);
        o[6] = (short)f2bf(v.z * TWO_PI); o[7] = (short)f2bf(v.w * TWO_PI);
        w_out[i] = o;
    } else {
        int i = (b - WBLOCKS) * 256 + threadIdx.x;
        float4 u = xin[2 * i];
        float4 v = xin[2 * i + 1];
        o[0] = (short)f2bf(u.x); o[1] = (short)f2bf(u.y);
        o[2] = (short)f2bf(u.z); o[3] = (short)f2bf(u.w);
        o[4] = (short)f2bf(v.x); o[5] = (short)f2bf(v.y);
        o[6] = (short)f2bf(v.z); o[7] = (short)f2bf(v.w);
        x_out[i] = o;
    }
}

// async 16B global -> LDS (LDS dest = wave-uniform base + lane*16, enforced below)
__device__ __forceinline__ void g2l16(const ushort* g, ushort* l) {
    __builtin_amdgcn_global_load_lds(
        (const __attribute__((address_space(1))) unsigned int*)g,
        (__attribute__((address_space(3))) unsigned int*)l, 16, 0, 0);
}

// C[M,N] = A[M,K] * B[N,K]^T + bias[N];  A,B bf16 (bits), C f32.
// R5 WINNER restored verbatim (78.5 us, 875 TF = m97-structure plateau).
// 128x128 block tile, BK=64, double-buffered LDS (2 x (16+16) KB = 64 KB).
// Grid 512 = 2 blocks/CU (grid-capped; R6 proved shrinking BK to raise
// occupancy regresses — window length is the active ingredient, not blocks/CU).
// Swizzle: physical 16B segment p of row r holds logical segment p ^ (r&7).
__global__ __launch_bounds__(256, 2) void gemm_bt_kernel(
    const ushort* __restrict__ A,
    const ushort* __restrict__ B,
    const float* __restrict__ bias,
    float* __restrict__ C)
{
    __shared__ ushort As[2][128 * BK];   // 2 x 16 KiB
    __shared__ ushort Bs[2][128 * BK];   // 2 x 16 KiB

    const int tid  = threadIdx.x;
    const int lane = tid & 63;
    const int wid  = tid >> 6;
    const int bn   = blockIdx.x;
    const int bm   = blockIdx.y;
    const int wm   = (wid >> 1) << 6;    // 0/64
    const int wn   = (wid & 1) << 6;     // 0/64
    const int fm   = lane & 15;
    const int q    = lane >> 4;          // 0..3

    // staging: wave-instr u covers 64 consecutive 16B chunks; chunk c = row*8+pseg,
    // lane = (row&7)*8 + pseg. Global source segment = pseg ^ (row&7).
    const int gcol = (((lane & 7) ^ (lane >> 3)) << 3);  // swizzled elem offset in row

    const ushort* gA = A + (size_t)(bm * 128) * IN_F;
    const ushort* gB = B + (size_t)(bn * 128) * IN_F;

    floatx4 acc[4][4];
#pragma unroll
    for (int i = 0; i < 4; i++)
#pragma unroll
        for (int j = 0; j < 4; j++)
            acc[i][j] = (floatx4){0.f, 0.f, 0.f, 0.f};

#define STAGE(k0v, bufi)                                                      \
    {                                                                         \
        _Pragma("unroll")                                                     \
        for (int u = 0; u < 4; u++) {                                         \
            const int cb = ((u << 2) | wid) << 6;   /* chunk base */          \
            const int r  = (cb >> 3) + (lane >> 3); /* row 0..127 */          \
            g2l16(gA + (size_t)r * IN_F + (k0v) + gcol,                       \
                  &As[bufi][cb * 8 + lane * 8]);                              \
            g2l16(gB + (size_t)r * IN_F + (k0v) + gcol,                       \
                  &Bs[bufi][cb * 8 + lane * 8]);                              \
        }                                                                     \
    }

#define COMPUTE(bufi)                                                         \
    {                                                                         \
        _Pragma("unroll")                                                     \
        for (int s = 0; s < 2; s++) {                                         \
            short8 af[4], bf[4];                                              \
            const int sa = (((q + 4 * s) & 7) ^ (fm & 7)) << 3;               \
            _Pragma("unroll")                                                 \
            for (int i = 0; i < 4; i++) {                                     \
                af[i] = *(const short8*)&As[bufi][(wm + i * 16 + fm) * BK + sa]; \
                bf[i] = *(const short8*)&Bs[bufi][(wn + i * 16 + fm) * BK + sa]; \
            }                                                                 \
            _Pragma("unroll")                                                 \
            for (int i = 0; i < 4; i++)                                       \
                _Pragma("unroll")                                             \
                for (int j = 0; j < 4; j++)                                   \
                    acc[i][j] = __builtin_amdgcn_mfma_f32_16x16x32_bf16(      \
                        af[i], bf[j], acc[i][j], 0, 0, 0);                    \
        }                                                                     \
    }

    STAGE(0, 0);
    __syncthreads();
    STAGE(BK, 1);
    COMPUTE(0);
    __syncthreads();
    // 31 pairs: slabs 128..4032
    for (int k0 = 2 * BK; k0 < IN_F; k0 += 2 * BK) {
        STAGE(k0, 0);
        COMPUTE(1);
        __syncthreads();
        STAGE(k0 + BK, 1);
        COMPUTE(0);
        __syncthreads();
    }
    COMPUTE(1);

#undef STAGE
#undef COMPUTE

    // epilogue: C/D layout col = lane&15, row = (lane>>4)*4 + reg  [m89-verified]
    const int cn = lane & 15;
    const int cm = (lane >> 4) << 2;
    float bv[4];
#pragma unroll
    for (int j = 0; j < 4; j++)
        bv[j] = bias[bn * 128 + wn + j * 16 + cn];
#pragma unroll
    for (int i = 0; i < 4; i++) {
#pragma unroll
        for (int r = 0; r < 4; r++) {
            int m = bm * 128 + wm + i * 16 + cm + r;
            float* crow = C + (size_t)m * OUT_F + bn * 128 + wn + cn;
#pragma unroll
            for (int j = 0; j < 4; j++)
                crow[j * 16] = acc[i][j][r] + bv[j];
        }
    }
}

extern "C" void kernel_launch(void* const* d_in, const int* in_sizes, int n_in,
                              void* d_out, int out_size, void* d_ws, size_t ws_size,
                              hipStream_t stream) {
    const float* x    = (const float*)d_in[0];   // [2048, 4096]
    const float* seed = (const float*)d_in[1];   // [4096, 4096]
    const float* da   = (const float*)d_in[2];   // [20]
    const float* db   = (const float*)d_in[3];   // [20]
    const float* bias = (const float*)d_in[4];   // [4096]
    float* out        = (float*)d_out;           // [2048, 4096]

    ushort* w_bf = (ushort*)d_ws;                      // 32 MiB
    ushort* x_bf = w_bf + (size_t)OUT_F * IN_F;        // 16 MiB

    transcribe_fused_kernel<<<WBLOCKS + XBLOCKS, 256, 0, stream>>>(
        (const float4*)seed, (const float4*)x, da, db,
        (short8*)w_bf, (short8*)x_bf);

    dim3 grid(OUT_F / 128, TOKENS / 128);  // (32, 16) = 512 blocks
    gemm_bt_kernel<<<grid, 256, 0, stream>>>(x_bf, w_bf, bias, out);
}